// Round 1
// baseline (176.920 us; speedup 1.0000x reference)
//
#include <hip/hip_runtime.h>
#include <hip/hip_bf16.h>
#include <cstdint>

// DST-II as GEMM: Y[m][k] = sum_n X[m][n] * S[n][k],
// S[n][k] = sin(pi/N * (n+0.5) * (k+1)), N = 1024.
// We compute St[k][n] = S[n][k] (B^T layout) in bf16 into d_ws, then run a
// 128x128 MFMA bf16 GEMM (m97-style structure) with fp32->bf16 A conversion
// fused into the LDS staging.

#define M_TOT 16384
#define N_TOT 1024
#define K_TOT 1024

typedef __attribute__((ext_vector_type(8), may_alias)) __bf16 bf16x8;
typedef __attribute__((ext_vector_type(8), may_alias)) short s16x8;
typedef __attribute__((ext_vector_type(4))) float f32x4;

__device__ __forceinline__ unsigned short f2bf(float f) {
  unsigned int b = __float_as_uint(f);
  b += 0x7fffu + ((b >> 16) & 1u);   // RNE
  return (unsigned short)(b >> 16);
}

__device__ __forceinline__ void gl_lds16(const void* g, void* l) {
  __builtin_amdgcn_global_load_lds(
      (const __attribute__((address_space(1))) unsigned int*)(uintptr_t)g,
      (__attribute__((address_space(3))) unsigned int*)(uintptr_t)l,
      16, 0, 0);
}

// St[j][n] = sin(pi*(2n+1)*(j+1)/2048), bf16, row-major [1024][1024].
// Exact range reduction: (2n+1)(j+1) mod 4096 -> revolutions r/4096 in [0,1).
__global__ void gen_st(unsigned short* __restrict__ st) {
  const int idx = blockIdx.x * 256 + threadIdx.x;
  const int base = idx * 8;             // 8 consecutive n for one j
  const int j = base >> 10;
  const int n0 = base & 1023;
  const int jj = j + 1;
  unsigned int pk[4];
#pragma unroll
  for (int t = 0; t < 4; ++t) {
    int n = n0 + 2 * t;
    int r0 = ((2 * n + 1) * jj) & 4095;
    int r1 = ((2 * n + 3) * jj) & 4095;
    unsigned short lo = f2bf(__builtin_amdgcn_sinf((float)r0 * (1.0f / 4096.0f)));
    unsigned short hi = f2bf(__builtin_amdgcn_sinf((float)r1 * (1.0f / 4096.0f)));
    pk[t] = (unsigned int)lo | ((unsigned int)hi << 16);
  }
  *(uint4*)(st + base) = make_uint4(pk[0], pk[1], pk[2], pk[3]);
}

// C[m][j] = sum_n A[m][n] * Bt[j][n];  A fp32 [16384][1024], Bt bf16 [1024][1024]
// Block: 256 threads (4 waves), tile 128(M) x 128(N), BK=64, 16 K-iters.
// LDS tiles row-major 128 x 64 bf16 (128 B rows = 8 x 16B chunks), with chunk
// XOR swizzle: data chunk c of row r is stored at chunk position c ^ (r & 7).
__global__ __launch_bounds__(256) void dst_gemm(
    const float* __restrict__ X, const unsigned short* __restrict__ St,
    float* __restrict__ Y) {
  __shared__ short As[128 * 64];
  __shared__ short Bs[128 * 64];

  const int t = threadIdx.x;
  const int l = t & 63;
  const int w = t >> 6;
  const int bN = blockIdx.x * 128;   // output-column block (8)
  const int bM = blockIdx.y * 128;   // batch-row block (128)
  const int wm = (w >> 1) * 64;
  const int wn = (w & 1) * 64;
  const int quad = l >> 4;
  const int l15 = l & 15;

  f32x4 acc[4][4] = {};

  for (int k0 = 0; k0 < K_TOT; k0 += 64) {
    // ---- B tile: async global->LDS, 16 B per lane, 4 issues/thread ----
    // LDS position p (16B chunks) is forced linear by global_load_lds; we
    // permute the *source* chunk so LDS holds the swizzled layout.
#pragma unroll
    for (int i = 0; i < 4; ++i) {
      int p = i * 256 + t;
      int r = p >> 3;            // tile row 0..127
      int c_lds = p & 7;         // chunk position
      int c_g = c_lds ^ (r & 7); // which data chunk lives here
      const unsigned short* src = St + ((bN + r) * K_TOT + k0 + c_g * 8);
      gl_lds16(src, &Bs[p * 8]);
    }
    // ---- A tile: fp32 load -> bf16 convert -> swizzled ds_write_b128 ----
#pragma unroll
    for (int i = 0; i < 4; ++i) {
      int p = i * 256 + t;
      int r = p >> 3;
      int c = p & 7;
      const float* src = X + ((size_t)(bM + r) * K_TOT + k0 + c * 8);
      float4 v0 = *(const float4*)(src);
      float4 v1 = *(const float4*)(src + 4);
      s16x8 pk;
      pk[0] = (short)f2bf(v0.x); pk[1] = (short)f2bf(v0.y);
      pk[2] = (short)f2bf(v0.z); pk[3] = (short)f2bf(v0.w);
      pk[4] = (short)f2bf(v1.x); pk[5] = (short)f2bf(v1.y);
      pk[6] = (short)f2bf(v1.z); pk[7] = (short)f2bf(v1.w);
      *(s16x8*)&As[r * 64 + ((c ^ (r & 7)) * 8)] = pk;
    }
    __syncthreads();

    // ---- compute: 2 sub-steps of K=32, 16 MFMA each ----
#pragma unroll
    for (int s = 0; s < 2; ++s) {
      const int cc = s * 4 + quad;   // data chunk holding k = s*32+quad*8..+7
      bf16x8 af[4], bfr[4];
#pragma unroll
      for (int mi = 0; mi < 4; ++mi) {
        int mrow = wm + mi * 16 + l15;
        af[mi] = *(const bf16x8*)&As[mrow * 64 + ((cc ^ (mrow & 7)) * 8)];
      }
#pragma unroll
      for (int ni = 0; ni < 4; ++ni) {
        int nrow = wn + ni * 16 + l15;
        bfr[ni] = *(const bf16x8*)&Bs[nrow * 64 + ((cc ^ (nrow & 7)) * 8)];
      }
#pragma unroll
      for (int mi = 0; mi < 4; ++mi)
#pragma unroll
        for (int ni = 0; ni < 4; ++ni)
          acc[mi][ni] = __builtin_amdgcn_mfma_f32_16x16x32_bf16(
              af[mi], bfr[ni], acc[mi][ni], 0, 0, 0);
    }
    __syncthreads();
  }

  // ---- epilogue: C/D layout col = lane&15, row = quad*4 + reg ----
#pragma unroll
  for (int mi = 0; mi < 4; ++mi) {
#pragma unroll
    for (int ni = 0; ni < 4; ++ni) {
#pragma unroll
      for (int rr = 0; rr < 4; ++rr) {
        int gr = bM + wm + mi * 16 + quad * 4 + rr;
        int gc = bN + wn + ni * 16 + l15;
        Y[(size_t)gr * N_TOT + gc] = acc[mi][ni][rr];
      }
    }
  }
}

extern "C" void kernel_launch(void* const* d_in, const int* in_sizes, int n_in,
                              void* d_out, int out_size, void* d_ws, size_t ws_size,
                              hipStream_t stream) {
  const float* X = (const float*)d_in[0];
  float* Y = (float*)d_out;
  unsigned short* St = (unsigned short*)d_ws;   // 1024*1024 bf16 = 2 MiB

  gen_st<<<dim3(512), dim3(256), 0, stream>>>(St);

  dim3 grid(N_TOT / 128, M_TOT / 128);  // (8, 128)
  dst_gemm<<<grid, dim3(256), 0, stream>>>(X, St, Y);
}

// Round 2
// 151.287 us; speedup vs baseline: 1.1694x; 1.1694x over previous
//
#include <hip/hip_runtime.h>
#include <hip/hip_bf16.h>
#include <cstdint>

// DST-II as GEMM: Y[m][k] = sum_n X[m][n] * S[n][k],
// S[n][k] = sin(pi/N * (n+0.5) * (k+1)), N = 1024.
// R2: tile 128Mx256N (512 thr, 8 waves as 2x4, wave tile 64x64), XCD-aware
// block swizzle so all 4 column-blocks of an X row-group share one XCD's L2.

#define M_TOT 16384
#define N_TOT 1024
#define K_TOT 1024

typedef __attribute__((ext_vector_type(8), may_alias)) __bf16 bf16x8;
typedef __attribute__((ext_vector_type(8), may_alias)) short s16x8;
typedef __attribute__((ext_vector_type(4))) float f32x4;

__device__ __forceinline__ unsigned short f2bf(float f) {
  unsigned int b = __float_as_uint(f);
  b += 0x7fffu + ((b >> 16) & 1u);   // RNE
  return (unsigned short)(b >> 16);
}

__device__ __forceinline__ void gl_lds16(const void* g, void* l) {
  __builtin_amdgcn_global_load_lds(
      (const __attribute__((address_space(1))) unsigned int*)(uintptr_t)g,
      (__attribute__((address_space(3))) unsigned int*)(uintptr_t)l,
      16, 0, 0);
}

// St[j][n] = sin(pi*(2n+1)*(j+1)/2048), bf16, row-major [1024][1024].
// Exact range reduction: (2n+1)(j+1) mod 4096 -> revolutions r/4096 in [0,1).
__global__ void gen_st(unsigned short* __restrict__ st) {
  const int idx = blockIdx.x * 256 + threadIdx.x;
  const int base = idx * 8;             // 8 consecutive n for one j
  const int j = base >> 10;
  const int n0 = base & 1023;
  const int jj = j + 1;
  unsigned int pk[4];
#pragma unroll
  for (int t = 0; t < 4; ++t) {
    int n = n0 + 2 * t;
    int r0 = ((2 * n + 1) * jj) & 4095;
    int r1 = ((2 * n + 3) * jj) & 4095;
    unsigned short lo = f2bf(__builtin_amdgcn_sinf((float)r0 * (1.0f / 4096.0f)));
    unsigned short hi = f2bf(__builtin_amdgcn_sinf((float)r1 * (1.0f / 4096.0f)));
    pk[t] = (unsigned int)lo | ((unsigned int)hi << 16);
  }
  *(uint4*)(st + base) = make_uint4(pk[0], pk[1], pk[2], pk[3]);
}

// C[m][j] = sum_n A[m][n] * Bt[j][n];  A fp32 [16384][1024], Bt bf16 [1024][1024]
// Block: 512 threads (8 waves, 2Mx4N), tile 128(M) x 256(N), BK=64, 16 K-iters.
// LDS tiles row-major, rows of 64 bf16 (128 B = 8 x 16B chunks), chunk XOR
// swizzle: data chunk c of row r stored at chunk position c ^ (r & 7).
__global__ __launch_bounds__(512, 4) void dst_gemm(
    const float* __restrict__ X, const unsigned short* __restrict__ St,
    float* __restrict__ Y) {
  __shared__ short As[128 * 64];   // 16 KB
  __shared__ short Bs[256 * 64];   // 32 KB

  const int t = threadIdx.x;
  const int l = t & 63;
  const int w = t >> 6;            // 0..7

  // XCD-aware swizzle: assume XCD = linear_block_id % 8.  512 blocks total.
  // XCD x handles bM-groups x*16 .. x*16+15, each with its 4 bN-blocks
  // consecutive in dispatch order (co-resident -> X rows served from L2).
  const int b = blockIdx.x;
  const int x = b & 7;
  const int s = b >> 3;            // 0..63
  const int bN = (s & 3) * 256;
  const int bM = (x * 16 + (s >> 2)) * 128;

  const int wm = (w >> 2) * 64;    // 0 or 64  (M within tile)
  const int wn = (w & 3) * 64;     // 0..192   (N within tile)
  const int quad = l >> 4;
  const int l15 = l & 15;

  f32x4 acc[4][4] = {};

  for (int k0 = 0; k0 < K_TOT; k0 += 64) {
    // ---- B tile: async global->LDS, 16 B/lane, 2048 chunks / 512 thr ----
#pragma unroll
    for (int i = 0; i < 4; ++i) {
      int p = i * 512 + t;
      int r = p >> 3;            // tile row 0..255
      int c_lds = p & 7;
      int c_g = c_lds ^ (r & 7); // source chunk that lives at this position
      const unsigned short* src = St + ((bN + r) * K_TOT + k0 + c_g * 8);
      gl_lds16(src, &Bs[p * 8]);
    }
    // ---- A tile: fp32 load -> bf16 -> swizzled ds_write_b128 ----
#pragma unroll
    for (int i = 0; i < 2; ++i) {
      int p = i * 512 + t;
      int r = p >> 3;            // 0..127
      int c = p & 7;
      const float* src = X + ((size_t)(bM + r) * K_TOT + k0 + c * 8);
      float4 v0 = *(const float4*)(src);
      float4 v1 = *(const float4*)(src + 4);
      s16x8 pk;
      pk[0] = (short)f2bf(v0.x); pk[1] = (short)f2bf(v0.y);
      pk[2] = (short)f2bf(v0.z); pk[3] = (short)f2bf(v0.w);
      pk[4] = (short)f2bf(v1.x); pk[5] = (short)f2bf(v1.y);
      pk[6] = (short)f2bf(v1.z); pk[7] = (short)f2bf(v1.w);
      *(s16x8*)&As[r * 64 + ((c ^ (r & 7)) * 8)] = pk;
    }
    __syncthreads();

    // ---- compute: 2 sub-steps of K=32, 16 MFMA each per wave ----
#pragma unroll
    for (int ss = 0; ss < 2; ++ss) {
      const int cc = ss * 4 + quad;   // data chunk holding k = ss*32+quad*8..+7
      bf16x8 af[4], bfr[4];
#pragma unroll
      for (int mi = 0; mi < 4; ++mi) {
        int mrow = wm + mi * 16 + l15;
        af[mi] = *(const bf16x8*)&As[mrow * 64 + ((cc ^ (mrow & 7)) * 8)];
      }
#pragma unroll
      for (int ni = 0; ni < 4; ++ni) {
        int nrow = wn + ni * 16 + l15;
        bfr[ni] = *(const bf16x8*)&Bs[nrow * 64 + ((cc ^ (nrow & 7)) * 8)];
      }
#pragma unroll
      for (int mi = 0; mi < 4; ++mi)
#pragma unroll
        for (int ni = 0; ni < 4; ++ni)
          acc[mi][ni] = __builtin_amdgcn_mfma_f32_16x16x32_bf16(
              af[mi], bfr[ni], acc[mi][ni], 0, 0, 0);
    }
    __syncthreads();
  }

  // ---- epilogue: C/D layout col = lane&15, row = quad*4 + reg ----
#pragma unroll
  for (int mi = 0; mi < 4; ++mi) {
#pragma unroll
    for (int ni = 0; ni < 4; ++ni) {
#pragma unroll
      for (int rr = 0; rr < 4; ++rr) {
        int gr = bM + wm + mi * 16 + quad * 4 + rr;
        int gc = bN + wn + ni * 16 + l15;
        Y[(size_t)gr * N_TOT + gc] = acc[mi][ni][rr];
      }
    }
  }
}

extern "C" void kernel_launch(void* const* d_in, const int* in_sizes, int n_in,
                              void* d_out, int out_size, void* d_ws, size_t ws_size,
                              hipStream_t stream) {
  const float* X = (const float*)d_in[0];
  float* Y = (float*)d_out;
  unsigned short* St = (unsigned short*)d_ws;   // 1024*1024 bf16 = 2 MiB

  gen_st<<<dim3(512), dim3(256), 0, stream>>>(St);

  dst_gemm<<<dim3(512), dim3(512), 0, stream>>>(X, St, Y);
}